// Round 1
// baseline (49191.714 us; speedup 1.0000x reference)
//
#include <hip/hip_runtime.h>
#include <stdint.h>

// LNN / echo-state layer: out[b,t,:] = h_{t+1},  h' = 0.8h + 0.2 tanh(x_t@W_in + h@W)
// Phase 1: xin = x @ W_in  (f32 tiled GEMM) written IN-PLACE into d_out.
// Phase 2: persistent recurrence kernel; W partitioned bf16 into LDS across 256 WGs,
//          per-step cross-WG h exchange via flags (agent-scope atomics) + bf16 hcast ring.

#define B_  32
#define T_  1024
#define D_  256
#define U_  1024
#define TU_ (T_ * U_)

// ---------------- Phase 1: xin = x @ W_in ----------------
#define P1_KC  32
#define P1_LDA 132   // padded LDS stride (f32 units)

__global__ __launch_bounds__(256) void k_xin_gemm(const float* __restrict__ x,
                                                  const float* __restrict__ win,
                                                  float* __restrict__ out) {
    __shared__ __align__(16) float xs[P1_KC * P1_LDA];  // [k][m] (transposed)
    __shared__ __align__(16) float ws[P1_KC * P1_LDA];  // [k][n]
    const int tid = threadIdx.x;
    const int m0 = (blockIdx.x >> 3) * 128;
    const int n0 = (blockIdx.x & 7) * 128;
    const int ty = tid >> 4;   // 0..15
    const int tx = tid & 15;   // 0..15

    float acc[8][8];
#pragma unroll
    for (int i = 0; i < 8; ++i)
#pragma unroll
        for (int j = 0; j < 8; ++j) acc[i][j] = 0.f;

    for (int k0 = 0; k0 < D_; k0 += P1_KC) {
        // stage x tile 128m x 32k, transposed into xs[k][m]
#pragma unroll
        for (int it = 0; it < 4; ++it) {
            int idx = it * 256 + tid;
            int m  = idx >> 3;
            int kq = idx & 7;
            float4 v = *reinterpret_cast<const float4*>(&x[(size_t)(m0 + m) * D_ + k0 + kq * 4]);
            xs[(kq * 4 + 0) * P1_LDA + m] = v.x;
            xs[(kq * 4 + 1) * P1_LDA + m] = v.y;
            xs[(kq * 4 + 2) * P1_LDA + m] = v.z;
            xs[(kq * 4 + 3) * P1_LDA + m] = v.w;
        }
        // stage W_in tile 32k x 128n
#pragma unroll
        for (int it = 0; it < 4; ++it) {
            int idx = it * 256 + tid;
            int r  = idx >> 5;
            int cq = idx & 31;
            float4 v = *reinterpret_cast<const float4*>(&win[(size_t)(k0 + r) * U_ + n0 + cq * 4]);
            *reinterpret_cast<float4*>(&ws[r * P1_LDA + cq * 4]) = v;
        }
        __syncthreads();
#pragma unroll
        for (int kk = 0; kk < P1_KC; ++kk) {
            float4 a0 = *reinterpret_cast<const float4*>(&xs[kk * P1_LDA + ty * 8]);
            float4 a1 = *reinterpret_cast<const float4*>(&xs[kk * P1_LDA + ty * 8 + 4]);
            float4 b0 = *reinterpret_cast<const float4*>(&ws[kk * P1_LDA + tx * 8]);
            float4 b1 = *reinterpret_cast<const float4*>(&ws[kk * P1_LDA + tx * 8 + 4]);
            float a[8] = {a0.x, a0.y, a0.z, a0.w, a1.x, a1.y, a1.z, a1.w};
            float b[8] = {b0.x, b0.y, b0.z, b0.w, b1.x, b1.y, b1.z, b1.w};
#pragma unroll
            for (int i = 0; i < 8; ++i)
#pragma unroll
                for (int j = 0; j < 8; ++j) acc[i][j] = fmaf(a[i], b[j], acc[i][j]);
        }
        __syncthreads();
    }
#pragma unroll
    for (int i = 0; i < 8; ++i) {
        size_t row = (size_t)(m0 + ty * 8 + i) * U_ + n0 + tx * 8;
        *reinterpret_cast<float4*>(&out[row])     = make_float4(acc[i][0], acc[i][1], acc[i][2], acc[i][3]);
        *reinterpret_cast<float4*>(&out[row + 4]) = make_float4(acc[i][4], acc[i][5], acc[i][6], acc[i][7]);
    }
}

// ---------------- Phase 2: persistent recurrence ----------------
// 4 domains x 64 WGs (contiguous blockIdx -> deadlock-safe), 16 cols/WG, 8 batches/domain.
#define NWG2  64
#define NC2   16
#define BPD2  8
#define BAIL_ (1u << 23)

__device__ __forceinline__ unsigned short f2bf(float v) {
    unsigned int bits = __float_as_uint(v);
    return (unsigned short)((bits + 0x7fffu + ((bits >> 16) & 1u)) >> 16);
}

__global__ __launch_bounds__(512) void k_recur(const float* __restrict__ W,
                                               float* __restrict__ out,
                                               unsigned int* __restrict__ flags,
                                               unsigned short* __restrict__ hcast) {
    __shared__ __align__(16) unsigned short Wl[NC2 * U_]; // 32 KB bf16, granule-swizzled
    __shared__ __align__(16) float hl[BPD2 * U_];         // 32 KB f32 (reused for partials)
    float* part = hl;  // [32 ks][8 b][16 c] after barrier

    const int tid = threadIdx.x;
    const int dom = blockIdx.x >> 6;        // 0..3
    const int wg  = blockIdx.x & 63;        // 0..63
    const int c0  = wg * NC2;
    const int b0  = dom * BPD2;

    // stage W columns [c0, c0+16) as bf16, XOR-swizzled granules of 8
    {
        const int c = tid & 15;
        for (int it = 0; it < 32; ++it) {
            int k = it * 32 + (tid >> 4);
            float v = W[(size_t)k * U_ + c0 + c];
            int g  = k >> 3;
            int gs = (g & ~15) | ((g ^ c) & 15);
            Wl[c * U_ + gs * 8 + (k & 7)] = f2bf(v);
        }
    }
    float hst = 0.f;   // per-thread state: tid<128 owns (b = tid>>4, c = tid&15)
    __syncthreads();

    const int cc = tid & 15;    // column
    const int ks = tid >> 4;    // 0..31, k-slice of 32

    for (int t = 0; t < T_; ++t) {
        float acc[BPD2];
#pragma unroll
        for (int b = 0; b < BPD2; ++b) acc[b] = 0.f;

        if (t > 0) {
            // wait for all 64 WGs' step t-1 of our domain's 8 batches
            if (tid < BPD2) {
                unsigned int* f = &flags[(t - 1) * 32 + b0 + tid];
                unsigned int spin = 0;
                while (__hip_atomic_load(f, __ATOMIC_ACQUIRE, __HIP_MEMORY_SCOPE_AGENT) < NWG2) {
                    __builtin_amdgcn_s_sleep(2);
                    if (++spin > BAIL_) break;  // safety: no infinite hang
                }
            }
            __syncthreads();
            // stage h (bf16 ring slot (t-1)&1) -> f32 LDS, ks-XOR de-conflict swizzle
            {
                const unsigned short* src = &hcast[((t - 1) & 1) * (32 * U_) + b0 * U_];
                for (int j = 0; j < 16; ++j) {
                    int idx = j * 512 + tid;          // 0..8191
                    int b = idx >> 10;
                    int k = idx & 1023;
                    int sk = k ^ (((k >> 6) & 3) << 3);
                    hl[b * U_ + sk] = __uint_as_float(((unsigned int)src[b * U_ + k]) << 16);
                }
            }
            __syncthreads();
            // inner: 4 granules of 8 k, 8 batches each
#pragma unroll
            for (int g8 = 0; g8 < 4; ++g8) {
                int g  = ks * 4 + g8;                       // granule 0..127
                int gs = (g & ~15) | ((g ^ cc) & 15);
                uint4 wv = *reinterpret_cast<const uint4*>(&Wl[cc * U_ + gs * 8]);
                float wf[8];
                wf[0] = __uint_as_float(wv.x << 16);  wf[1] = __uint_as_float(wv.x & 0xffff0000u);
                wf[2] = __uint_as_float(wv.y << 16);  wf[3] = __uint_as_float(wv.y & 0xffff0000u);
                wf[4] = __uint_as_float(wv.z << 16);  wf[5] = __uint_as_float(wv.z & 0xffff0000u);
                wf[6] = __uint_as_float(wv.w << 16);  wf[7] = __uint_as_float(wv.w & 0xffff0000u);
                int base = (g * 8) ^ (((g >> 3) & 3) << 3);
#pragma unroll
                for (int b = 0; b < BPD2; ++b) {
                    float4 h0 = *reinterpret_cast<const float4*>(&hl[b * U_ + base]);
                    float4 h1 = *reinterpret_cast<const float4*>(&hl[b * U_ + base + 4]);
                    float s = acc[b];
                    s = fmaf(wf[0], h0.x, s); s = fmaf(wf[1], h0.y, s);
                    s = fmaf(wf[2], h0.z, s); s = fmaf(wf[3], h0.w, s);
                    s = fmaf(wf[4], h1.x, s); s = fmaf(wf[5], h1.y, s);
                    s = fmaf(wf[6], h1.z, s); s = fmaf(wf[7], h1.w, s);
                    acc[b] = s;
                }
            }
            __syncthreads();   // before reusing hl as partial buffer
#pragma unroll
            for (int b = 0; b < BPD2; ++b)
                part[(ks * 8 + b) * 16 + cc] = acc[b];
            __syncthreads();
        }

        // finalize: tid<128 owns (b, c); reduce 32 k-slices, apply leak+tanh, publish
        if (tid < 128) {
            const int c = tid & 15;
            const int b = tid >> 4;
            float s = 0.f;
            if (t > 0) {
#pragma unroll
                for (int k2 = 0; k2 < 32; ++k2) s += part[(k2 * 8 + b) * 16 + c];
            }
            size_t o = (size_t)(b0 + b) * TU_ + (size_t)t * U_ + c0 + c;
            float xin = out[o];                      // phase-1 result (in-place)
            float hn  = 0.8f * hst + 0.2f * tanhf(xin + s);
            hst = hn;
            out[o] = hn;
            hcast[(t & 1) * (32 * U_) + (size_t)(b0 + b) * U_ + c0 + c] = f2bf(hn);
        }
        __threadfence();        // make out/hcast stores agent-visible
        __syncthreads();
        if (tid < BPD2) {
            __hip_atomic_fetch_add(&flags[t * 32 + b0 + tid], 1u,
                                   __ATOMIC_RELEASE, __HIP_MEMORY_SCOPE_AGENT);
        }
    }
}

extern "C" void kernel_launch(void* const* d_in, const int* in_sizes, int n_in,
                              void* d_out, int out_size, void* d_ws, size_t ws_size,
                              hipStream_t stream) {
    const float* x   = (const float*)d_in[0];   // [32,1024,256]
    const float* W   = (const float*)d_in[1];   // [1024,1024]
    const float* win = (const float*)d_in[2];   // [256,1024]
    float* out = (float*)d_out;                 // [32,1024,1024]

    // ws layout: [0,128K) flags (1024*32 u32), [128K,256K) hcast ring (2*32*1024 bf16)
    unsigned int*   flags = (unsigned int*)d_ws;
    unsigned short* hcast = (unsigned short*)((char*)d_ws + 131072);
    if (ws_size < 262144) return;  // loud failure if scratch too small

    hipMemsetAsync(d_ws, 0, 131072, stream);                        // zero flags every call
    k_xin_gemm<<<dim3(2048), dim3(256), 0, stream>>>(x, win, out);  // xin -> d_out
    k_recur<<<dim3(256), dim3(512), 0, stream>>>(W, out, flags, hcast);
}

// Round 2
// 4877.760 us; speedup vs baseline: 10.0849x; 10.0849x over previous
//
#include <hip/hip_runtime.h>
#include <stdint.h>

// Echo-state recurrence h' = 0.8h + 0.2*tanh(x_t@W_in + h@W), out[b,t,:]=h'.
// Single persistent kernel. 8 domains x 32 WGs; each WG: 4 batches, 32 cols.
// W (f16) + W_in (f32) resident in LDS. Cross-WG h exchange per step through
// L3 via RELAXED agent-scope atomics (sc1, no L2 inv/wb storms), flag per
// (domain,step), producer order via s_waitcnt vmcnt(0) before relaxed add.

#define B_   32
#define T_   1024
#define D_   256
#define U_   1024

#define NDOM 8
#define WPD  32     // WGs per domain
#define BPD  4      // batches per domain
#define NC   32     // cols per WG
#define NTHR 512
#define BAIL (1u << 22)

#define LDS_BYTES 119040
// carve: Wl 65536 | Winl 32768 | part 8192 | hl 8192 | xl 4096 | hb 256

typedef _Float16 half2v __attribute__((ext_vector_type(2)));

#if defined(__has_builtin) && __has_builtin(__builtin_amdgcn_fdot2)
#define HAS_FDOT2 1
#else
#define HAS_FDOT2 0
#endif

__device__ __forceinline__ float dot2acc(unsigned int h2, unsigned int w2, float acc) {
#if HAS_FDOT2
    return __builtin_amdgcn_fdot2(__builtin_bit_cast(half2v, h2),
                                  __builtin_bit_cast(half2v, w2), acc, false);
#else
    half2v h = __builtin_bit_cast(half2v, h2);
    half2v w = __builtin_bit_cast(half2v, w2);
    acc = fmaf((float)h.x, (float)w.x, acc);
    return fmaf((float)h.y, (float)w.y, acc);
#endif
}

__global__ __launch_bounds__(NTHR) void k_recur(const float* __restrict__ x,
                                                const float* __restrict__ W,
                                                const float* __restrict__ win,
                                                float* __restrict__ out,
                                                unsigned int* __restrict__ flags,
                                                unsigned long long* __restrict__ hcast) {
    extern __shared__ __align__(16) char smem[];
    unsigned short* Wl   = (unsigned short*)smem;             // [32 c][128 u4][8 f16] swz
    float*          Winl = (float*)(smem + 65536);            // [32 c][64 f4][4 f32] swz
    float*          part = (float*)(smem + 98304);            // [16 ks][4 b][32 c]
    unsigned short* hl   = (unsigned short*)(smem + 106496);  // [4 b][1024 k] f16
    float*          xl   = (float*)(smem + 114688);           // [4 b][256 k] f32
    unsigned short* hb   = (unsigned short*)(smem + 118784);  // [32 c][4 b] f16

    const uint4*  Wl4   = (const uint4*)Wl;
    const float4* Winl4 = (const float4*)Winl;
    const uint4*  hl4   = (const uint4*)hl;
    const float4* xl4   = (const float4*)xl;

    const int tid = threadIdx.x;
    const int dom = blockIdx.x >> 5;   // 0..7
    const int wg  = blockIdx.x & 31;   // 0..31
    const int c0  = wg * NC;
    const int b0  = dom * BPD;

    // ---- one-time stage: W cols -> f16 LDS (16B-granule XOR swizzle), W_in -> f32 LDS ----
    {
        const int c = tid & 31, kk = tid >> 5;   // 16 k-rows per iteration
        for (int it = 0; it < 64; ++it) {
            int k = it * 16 + kk;
            _Float16 hv = (_Float16)W[(size_t)k * U_ + c0 + c];
            int qs = (k >> 3) ^ (c & 7);
            Wl[(c * 128 + qs) * 8 + (k & 7)] = __builtin_bit_cast(unsigned short, hv);
        }
        for (int it = 0; it < 16; ++it) {
            int k = it * 16 + kk;
            float v = win[(size_t)k * U_ + c0 + c];
            int qs = (k >> 2) ^ (c & 7);
            Winl[(c * 64 + qs) * 4 + (k & 3)] = v;
        }
    }
    float hst = 0.f;   // state for finalize threads (tid<128: b=tid>>5, c=tid&31)
    __syncthreads();

    const int cc = tid & 31;
    const int ks = tid >> 5;   // 0..15 (64-k slice for W, 16-k slice for W_in)

    for (int t = 0; t < T_; ++t) {
        // ---- stage x[b0..b0+3, t, :] -> xl (plain cached loads, coalesced) ----
        {
            int b = tid >> 7, k2 = tid & 127;
            *(float2*)&xl[b * D_ + k2 * 2] =
                *(const float2*)&x[((size_t)(b0 + b) * T_ + t) * D_ + k2 * 2];
        }
        __syncthreads();   // (1) xl ready

        float acc[BPD];
#pragma unroll
        for (int b = 0; b < BPD; ++b) acc[b] = 0.f;

        // ---- xin partial (h-independent; overlaps the flag wait latency) ----
#pragma unroll
        for (int q = 0; q < 4; ++q) {
            int qs = ((ks << 2) + q) ^ (cc & 7);
            float4 wv = Winl4[cc * 64 + qs];
#pragma unroll
            for (int b = 0; b < BPD; ++b) {
                float4 xv = xl4[b * 64 + (ks << 2) + q];
                float s = acc[b];
                s = fmaf(wv.x, xv.x, s);
                s = fmaf(wv.y, xv.y, s);
                s = fmaf(wv.z, xv.z, s);
                s = fmaf(wv.w, xv.w, s);
                acc[b] = s;
            }
        }

        if (t > 0) {
            // ---- wait for all 32 WGs of our domain to publish step t-1 ----
            if (tid == 0) {
                unsigned int* f = &flags[(t - 1) * NDOM + dom];
                unsigned int spin = 0;
                while (__hip_atomic_load(f, __ATOMIC_RELAXED, __HIP_MEMORY_SCOPE_AGENT) < WPD) {
                    __builtin_amdgcn_s_sleep(1);
                    if (++spin > BAIL) break;   // safety: never hang
                }
            }
            __syncthreads();   // (2) flag observed
            // ---- stage hcast slot (t-1)&1 -> hl [b][k] f16 ----
            {
                const unsigned long long* src = &hcast[((t - 1) & 1) * 8192 + dom * 1024];
#pragma unroll
                for (int r = 0; r < 2; ++r) {
                    int j = r * NTHR + tid;   // col 0..1023
                    unsigned long long v =
                        __hip_atomic_load(&src[j], __ATOMIC_RELAXED, __HIP_MEMORY_SCOPE_AGENT);
                    hl[0 * 1024 + j] = (unsigned short)(v);
                    hl[1 * 1024 + j] = (unsigned short)(v >> 16);
                    hl[2 * 1024 + j] = (unsigned short)(v >> 32);
                    hl[3 * 1024 + j] = (unsigned short)(v >> 48);
                }
            }
            __syncthreads();   // (3) hl ready
            // ---- W-phase: dot2 f16, 64-k slice per thread, 4 batches ----
#pragma unroll
            for (int jq = 0; jq < 8; ++jq) {
                int qs = ((ks << 3) + jq) ^ (cc & 7);
                uint4 w4 = Wl4[cc * 128 + qs];
#pragma unroll
                for (int b = 0; b < BPD; ++b) {
                    uint4 h4 = hl4[b * 128 + (ks << 3) + jq];
                    float s = acc[b];
                    s = dot2acc(h4.x, w4.x, s);
                    s = dot2acc(h4.y, w4.y, s);
                    s = dot2acc(h4.z, w4.z, s);
                    s = dot2acc(h4.w, w4.w, s);
                    acc[b] = s;
                }
            }
        }

#pragma unroll
        for (int b = 0; b < BPD; ++b)
            part[(ks * BPD + b) * NC + cc] = acc[b];
        __syncthreads();   // (4) partials ready

        // ---- finalize: reduce 16 k-slices, leak+tanh, store out + hb ----
        if (tid < 128) {
            int c = tid & 31, b = tid >> 5;
            float s = 0.f;
#pragma unroll
            for (int k2 = 0; k2 < 16; ++k2) s += part[(k2 * BPD + b) * NC + c];
            float hn = 0.8f * hst + 0.2f * tanhf(s);
            hst = hn;
            out[((size_t)(b0 + b) * T_ + t) * U_ + c0 + c] = hn;
            _Float16 hf = (_Float16)hn;
            hb[c * BPD + b] = __builtin_bit_cast(unsigned short, hf);
        }
        __syncthreads();   // (5) hb ready

        // ---- publish: wave 0 stores 32x u64 (sc1), vmcnt ack, relaxed flag add ----
        if (tid < 32) {
            unsigned long long vv = ((const unsigned long long*)hb)[tid];
            __hip_atomic_store(&hcast[(t & 1) * 8192 + dom * 1024 + c0 + tid], vv,
                               __ATOMIC_RELAXED, __HIP_MEMORY_SCOPE_AGENT);
            asm volatile("s_waitcnt vmcnt(0)" ::: "memory");
            if (tid == 0)
                __hip_atomic_fetch_add(&flags[t * NDOM + dom], 1u,
                                       __ATOMIC_RELAXED, __HIP_MEMORY_SCOPE_AGENT);
        }
    }
}

extern "C" void kernel_launch(void* const* d_in, const int* in_sizes, int n_in,
                              void* d_out, int out_size, void* d_ws, size_t ws_size,
                              hipStream_t stream) {
    const float* x   = (const float*)d_in[0];   // [32,1024,256]
    const float* W   = (const float*)d_in[1];   // [1024,1024]
    const float* win = (const float*)d_in[2];   // [256,1024]
    float* out = (float*)d_out;                 // [32,1024,1024]

    // ws: [0,32K) flags (1024*8 u32), [32K,160K) hcast ring (2*8192 u64)
    unsigned int*       flags = (unsigned int*)d_ws;
    unsigned long long* hcast = (unsigned long long*)((char*)d_ws + 32768);
    if (ws_size < 163840) return;

    hipFuncSetAttribute(reinterpret_cast<const void*>(k_recur),
                        hipFuncAttributeMaxDynamicSharedMemorySize, LDS_BYTES);
    hipMemsetAsync(d_ws, 0, 32768, stream);   // zero flags every call (replay-safe)
    k_recur<<<dim3(NDOM * WPD), dim3(NTHR), LDS_BYTES, stream>>>(x, W, win, out, flags, hcast);
}

// Round 3
// 3398.683 us; speedup vs baseline: 14.4738x; 1.4352x over previous
//
#include <hip/hip_runtime.h>
#include <stdint.h>

// Echo-state recurrence h' = 0.8h + 0.2*tanh(x_t@W_in + h@W), out[b,t,:]=h'.
// Persistent kernel: 8 domains x 32 WGs; WG = 4 batches x 32 cols, W(f16)+W_in(f32) in LDS.
// Sync per step: per-WG flag slot (relaxed store) + 32-lane parallel poll; hcast u64 ring
// through L3 (relaxed agent atomics, sc1). x[t+1] prefetched into regs during step t.

#define B_   32
#define T_   1024
#define D_   256
#define U_   1024

#define NDOM 8
#define WPD  32
#define BPD  4
#define NC   32
#define NTHR 512
#define BAIL (1u << 22)

#define LDS_BYTES 118784
// carve: Wl 65536 | Winl 32768 | part4 8192 | hl 8192 | xl 4096

typedef _Float16 half2v __attribute__((ext_vector_type(2)));

#if defined(__has_builtin) && __has_builtin(__builtin_amdgcn_fdot2)
#define HAS_FDOT2 1
#else
#define HAS_FDOT2 0
#endif

__device__ __forceinline__ float dot2acc(unsigned int h2, unsigned int w2, float acc) {
#if HAS_FDOT2
    return __builtin_amdgcn_fdot2(__builtin_bit_cast(half2v, h2),
                                  __builtin_bit_cast(half2v, w2), acc, false);
#else
    half2v h = __builtin_bit_cast(half2v, h2);
    half2v w = __builtin_bit_cast(half2v, w2);
    acc = fmaf((float)h.x, (float)w.x, acc);
    return fmaf((float)h.y, (float)w.y, acc);
#endif
}

#if defined(__has_builtin) && __has_builtin(__builtin_amdgcn_rcpf)
__device__ __forceinline__ float rcp_fast(float v) { return __builtin_amdgcn_rcpf(v); }
#else
__device__ __forceinline__ float rcp_fast(float v) { return 1.f / v; }
#endif

__device__ __forceinline__ float tanh_fast(float v) {
    // 1 - 2/(e^{2v}+1); exact at +-inf, ~1e-6 abs err, far below tolerance
    float e = __expf(2.f * v);
    return 1.f - 2.f * rcp_fast(e + 1.f);
}

__global__ __launch_bounds__(NTHR) void k_recur(const float* __restrict__ x,
                                                const float* __restrict__ W,
                                                const float* __restrict__ win,
                                                float* __restrict__ out,
                                                unsigned int* __restrict__ flags,
                                                unsigned long long* __restrict__ hcast) {
    extern __shared__ __align__(16) char smem[];
    unsigned short* Wl    = (unsigned short*)smem;             // [32 c][128 q][8 f16] swz
    float*          Winl  = (float*)(smem + 65536);            // [32 c][64 q][4 f32] swz
    float4*         part4 = (float4*)(smem + 98304);           // [16 ks][32 c] float4(b0..b3)
    unsigned short* hl    = (unsigned short*)(smem + 106496);  // [4 b][1024 k] f16
    float*          xl    = (float*)(smem + 114688);           // [4 b][256 k] f32

    const uint4*   Wl4   = (const uint4*)Wl;
    const float4*  Winl4 = (const float4*)Winl;
    const uint4*   hl4   = (const uint4*)hl;
    const float4*  xl4   = (const float4*)xl;
    unsigned int*  hl32  = (unsigned int*)hl;

    const int tid = threadIdx.x;
    const int dom = blockIdx.x >> 5;   // 0..7
    const int wg  = blockIdx.x & 31;   // 0..31
    const int c0  = wg * NC;
    const int b0  = dom * BPD;

    // ---- one-time stage: W -> f16 LDS (16B-granule XOR swizzle), W_in -> f32 LDS ----
    {
        const int c = tid & 31, kk = tid >> 5;
        for (int it = 0; it < 64; ++it) {
            int k = it * 16 + kk;
            _Float16 hv = (_Float16)W[(size_t)k * U_ + c0 + c];
            int qs = (k >> 3) ^ (c & 7);
            Wl[(c * 128 + qs) * 8 + (k & 7)] = __builtin_bit_cast(unsigned short, hv);
        }
        for (int it = 0; it < 16; ++it) {
            int k = it * 16 + kk;
            float v = win[(size_t)k * U_ + c0 + c];
            int qs = (k >> 2) ^ (c & 7);
            Winl[(c * 64 + qs) * 4 + (k & 3)] = v;
        }
    }

    const int cc = tid & 31;
    const int ks = tid >> 5;    // 0..15
    const int xb = tid >> 7;    // 0..3
    const int xk = tid & 127;   // float2 index within row

    float hst0 = 0.f, hst1 = 0.f, hst2 = 0.f, hst3 = 0.f;  // tid<32 state (4 batches)
    float2 pre = *(const float2*)&x[((size_t)(b0 + xb) * T_) * D_ + xk * 2];
    *(float2*)&xl[xb * D_ + xk * 2] = pre;   // xl[t=0]; covered by sync (E) below

    for (int t = 0; t < T_; ++t) {
        __syncthreads();   // (E) xl[t] + staged LDS visible

        float acc[4] = {0.f, 0.f, 0.f, 0.f};

        // ---- xin partial (h-independent; before the wait) ----
#pragma unroll
        for (int q = 0; q < 4; ++q) {
            int qs = ((ks << 2) + q) ^ (cc & 7);
            float4 wv = Winl4[cc * 64 + qs];
#pragma unroll
            for (int b = 0; b < 4; ++b) {
                float4 xv = xl4[b * 64 + (ks << 2) + q];
                float s = acc[b];
                s = fmaf(wv.x, xv.x, s);
                s = fmaf(wv.y, xv.y, s);
                s = fmaf(wv.z, xv.z, s);
                s = fmaf(wv.w, xv.w, s);
                acc[b] = s;
            }
        }

        // ---- prefetch x[t+1] into regs (HBM latency hides under wait + W-phase) ----
        if (t + 1 < T_)
            pre = *(const float2*)&x[((size_t)(b0 + xb) * T_ + (t + 1)) * D_ + xk * 2];

        if (t > 0) {
            // ---- wait: 32 per-WG flag slots polled in parallel by wave 0 ----
            if (tid < 64) {
                unsigned int* f = &flags[dom * WPD + (tid & 31)];
                unsigned int spin = 0;
                while (__hip_atomic_load(f, __ATOMIC_RELAXED, __HIP_MEMORY_SCOPE_AGENT)
                       < (unsigned int)t) {
                    if (++spin > BAIL) break;   // safety: never hang
                }
            }
            __syncthreads();   // (A) flags observed
            // ---- stage hcast slot (t-1)&1 -> hl [b][k] f16 (both loads in flight) ----
            {
                const unsigned long long* src = &hcast[((t - 1) & 1) * 8192 + dom * 1024];
                unsigned long long v0 =
                    __hip_atomic_load(&src[2 * tid], __ATOMIC_RELAXED, __HIP_MEMORY_SCOPE_AGENT);
                unsigned long long v1 =
                    __hip_atomic_load(&src[2 * tid + 1], __ATOMIC_RELAXED, __HIP_MEMORY_SCOPE_AGENT);
#pragma unroll
                for (int b = 0; b < 4; ++b) {
                    unsigned int lo = (unsigned int)(v0 >> (16 * b)) & 0xffffu;
                    unsigned int hi = (unsigned int)(v1 >> (16 * b)) & 0xffffu;
                    hl32[b * 512 + tid] = lo | (hi << 16);
                }
            }
            __syncthreads();   // (B) hl ready
            // ---- W-phase: f16 dot2, 64-k slice per thread, 4 batches ----
#pragma unroll
            for (int jq = 0; jq < 8; ++jq) {
                int qs = ((ks << 3) + jq) ^ (cc & 7);
                uint4 w4 = Wl4[cc * 128 + qs];
#pragma unroll
                for (int b = 0; b < 4; ++b) {
                    uint4 h4 = hl4[b * 128 + (ks << 3) + jq];
                    float s = acc[b];
                    s = dot2acc(h4.x, w4.x, s);
                    s = dot2acc(h4.y, w4.y, s);
                    s = dot2acc(h4.z, w4.z, s);
                    s = dot2acc(h4.w, w4.w, s);
                    acc[b] = s;
                }
            }
        }

        part4[ks * 32 + cc] = make_float4(acc[0], acc[1], acc[2], acc[3]);
        __syncthreads();   // (C) partials ready

        // ---- write xl[t+1] from prefetch regs (all threads; xin reads are done) ----
        if (t + 1 < T_)
            *(float2*)&xl[xb * D_ + xk * 2] = pre;

        // ---- finalize + publish: wave-0 lanes 0..31, one column x 4 batches each ----
        if (tid < 32) {
            float s0 = 0.f, s1 = 0.f, s2 = 0.f, s3 = 0.f;
#pragma unroll
            for (int k2 = 0; k2 < 16; ++k2) {
                float4 v = part4[k2 * 32 + tid];
                s0 += v.x; s1 += v.y; s2 += v.z; s3 += v.w;
            }
            float h0 = 0.8f * hst0 + 0.2f * tanh_fast(s0);
            float h1 = 0.8f * hst1 + 0.2f * tanh_fast(s1);
            float h2 = 0.8f * hst2 + 0.2f * tanh_fast(s2);
            float h3 = 0.8f * hst3 + 0.2f * tanh_fast(s3);
            hst0 = h0; hst1 = h1; hst2 = h2; hst3 = h3;
            size_t ob = ((size_t)b0 * T_ + t) * U_ + c0 + tid;
            out[ob]              = h0;
            out[ob + (size_t)T_ * U_]     = h1;
            out[ob + (size_t)2 * T_ * U_] = h2;
            out[ob + (size_t)3 * T_ * U_] = h3;
            unsigned long long pk =
                  (unsigned long long)__builtin_bit_cast(unsigned short, (_Float16)h0)
                | ((unsigned long long)__builtin_bit_cast(unsigned short, (_Float16)h1) << 16)
                | ((unsigned long long)__builtin_bit_cast(unsigned short, (_Float16)h2) << 32)
                | ((unsigned long long)__builtin_bit_cast(unsigned short, (_Float16)h3) << 48);
            __hip_atomic_store(&hcast[(t & 1) * 8192 + dom * 1024 + c0 + tid], pk,
                               __ATOMIC_RELAXED, __HIP_MEMORY_SCOPE_AGENT);
            asm volatile("s_waitcnt vmcnt(0)" ::: "memory");   // payload at coherence point
            if (tid == 0)
                __hip_atomic_store(&flags[dom * WPD + wg], (unsigned int)(t + 1),
                                   __ATOMIC_RELAXED, __HIP_MEMORY_SCOPE_AGENT);
        }
    }
}

extern "C" void kernel_launch(void* const* d_in, const int* in_sizes, int n_in,
                              void* d_out, int out_size, void* d_ws, size_t ws_size,
                              hipStream_t stream) {
    const float* x   = (const float*)d_in[0];   // [32,1024,256]
    const float* W   = (const float*)d_in[1];   // [1024,1024]
    const float* win = (const float*)d_in[2];   // [256,1024]
    float* out = (float*)d_out;                 // [32,1024,1024]

    // ws: [0,4K) flags (256 u32 used), [4K,132K+4K) hcast ring (2*8192 u64)
    unsigned int*       flags = (unsigned int*)d_ws;
    unsigned long long* hcast = (unsigned long long*)((char*)d_ws + 4096);
    if (ws_size < 4096 + 2 * 8192 * 8) return;

    hipFuncSetAttribute(reinterpret_cast<const void*>(k_recur),
                        hipFuncAttributeMaxDynamicSharedMemorySize, LDS_BYTES);
    hipMemsetAsync(d_ws, 0, 4096, stream);   // zero flag slots every call (replay-safe)
    k_recur<<<dim3(NDOM * WPD), dim3(NTHR), LDS_BYTES, stream>>>(x, W, win, out, flags, hcast);
}

// Round 4
// 1515.513 us; speedup vs baseline: 32.4588x; 2.2426x over previous
//
#include <hip/hip_runtime.h>
#include <stdint.h>

// Echo-state recurrence h' = 0.8h + 0.2*tanh([h|x_t] @ [W;W_in]), out[b,t,:]=h'.
// Persistent kernel, 8 domains x 32 WGs (dom = blockIdx&7 -> XCD-aligned).
// WG = 4 batches x 32 cols. W/W_in live in VGPRs as MFMA B-fragments (f16).
// Sync: tag-in-data. Each h element published as u32 (f16<<16 | step tag) via
// fire-and-forget sc0sc1 store; consumers poll payload until all tags match.
// No flags, no acks, no memset. 2-slot ring; tag equality => replay-safe.

#define T_   1024
#define D_   256
#define U_   1024
#define NTHR 512
#define HLS  1296        // shorts per batch row: 1024 h + 256 x + 16 pad (2592 B)
#define BAIL 65536u

typedef _Float16     f16x8 __attribute__((ext_vector_type(8)));
typedef float        f32x4 __attribute__((ext_vector_type(4)));
typedef unsigned int u32x4 __attribute__((ext_vector_type(4)));

#if defined(__has_builtin) && __has_builtin(__builtin_amdgcn_rcpf)
__device__ __forceinline__ float rcp_fast(float v) { return __builtin_amdgcn_rcpf(v); }
#else
__device__ __forceinline__ float rcp_fast(float v) { return 1.f / v; }
#endif

__device__ __forceinline__ float tanh_fast(float v) {
    float e = __expf(2.f * v);             // v_exp_f32 path
    return 1.f - 2.f * rcp_fast(e + 1.f);  // ~1e-6 abs err, exact at +-inf
}

__global__ __launch_bounds__(NTHR, 2) void k_recur(const float* __restrict__ x,
                                                   const float* __restrict__ W,
                                                   const float* __restrict__ win,
                                                   float* __restrict__ out,
                                                   u32x4* __restrict__ hc) {
    __shared__ short hl16[4 * HLS];   // [4 b][1024 h | 256 x | pad] f16
    __shared__ f32x4 part4[256];      // [8 wave][32 col] -> (b0..b3)
    unsigned int* hl32 = (unsigned int*)hl16;

    const int tid  = threadIdx.x;
    const int dom  = blockIdx.x & 7;   // XCD-aligned domains (perf heuristic only)
    const int wg   = blockIdx.x >> 3;  // 0..31
    const int c0   = wg * 32;
    const int b0   = dom * 4;
    const int lane = tid & 63;
    const int wv   = tid >> 6;         // wave 0..7 owns K slice [wv*128,+128) + x[wv*32,+32)
    const int l15  = lane & 15;
    const int lg   = lane >> 4;        // k-group 0..3

    // ---- one-time: W / W_in -> register B-fragments (f16), B[k][col] layout ----
    f16x8 bw[5][2];
#pragma unroll
    for (int kt = 0; kt < 4; ++kt)
#pragma unroll
        for (int ct = 0; ct < 2; ++ct)
#pragma unroll
            for (int j = 0; j < 8; ++j)
                bw[kt][ct][j] =
                    (_Float16)W[(size_t)(wv * 128 + kt * 32 + lg * 8 + j) * U_ + c0 + ct * 16 + l15];
#pragma unroll
    for (int ct = 0; ct < 2; ++ct)
#pragma unroll
        for (int j = 0; j < 8; ++j)
            bw[4][ct][j] =
                (_Float16)win[(size_t)(wv * 32 + lg * 8 + j) * U_ + c0 + ct * 16 + l15];

    // zero hl (h region must be 0 for t=0; x region overwritten each step)
    for (int i = tid; i < 2 * HLS; i += NTHR) hl32[i] = 0;

    const int xb = tid >> 7, xk = tid & 127;
    float2 pre = *(const float2*)&x[((size_t)(b0 + xb) * T_) * D_ + xk * 2];

    const int abase = (l15 & 3) * HLS + lg * 8;   // A-frag: row=batch(row&3), k-group lg

    float hs0 = 0.f, hs1 = 0.f, hs2 = 0.f, hs3 = 0.f;   // tid<32: state for 4 batches

    for (int t = 0; t < T_; ++t) {
        __syncthreads();   // (E) prev MFMA done -> hl writable; part reads done

        // x[t] f32 -> f16 pair into hl
        {
            unsigned a = (unsigned)__builtin_bit_cast(unsigned short, (_Float16)pre.x);
            unsigned b = (unsigned)__builtin_bit_cast(unsigned short, (_Float16)pre.y);
            hl32[xb * (HLS / 2) + 512 + xk] = a | (b << 16);
        }
        if (t + 1 < T_)   // prefetch next x (HBM latency hides under poll+MFMA)
            pre = *(const float2*)&x[((size_t)(b0 + xb) * T_ + (t + 1)) * D_ + xk * 2];

        if (t > 0) {
            // ---- poll payload: 2 cols x 4 batches, tags must equal t ----
            const u32x4* pp = hc + (size_t)((t & 1) * 8192 + dom * 1024 + 2 * tid);
            u32x4 va, vb;
            unsigned spin = 0;
            int ok;
            do {
                asm volatile(
                    "global_load_dwordx4 %0, %2, off sc0 sc1\n\t"
                    "global_load_dwordx4 %1, %2, off offset:16 sc0 sc1\n\t"
                    "s_waitcnt vmcnt(0)"
                    : "=&v"(va), "=&v"(vb) : "v"(pp) : "memory");
                unsigned tg = (unsigned)t;
                ok = ((va[0] & 0xffffu) == tg) & ((va[1] & 0xffffu) == tg) &
                     ((va[2] & 0xffffu) == tg) & ((va[3] & 0xffffu) == tg) &
                     ((vb[0] & 0xffffu) == tg) & ((vb[1] & 0xffffu) == tg) &
                     ((vb[2] & 0xffffu) == tg) & ((vb[3] & 0xffffu) == tg);
            } while (!__all(ok) && ++spin < BAIL);
            // h f16 (hi16) -> hl shorts [2tid], [2tid+1] per batch
#pragma unroll
            for (int b = 0; b < 4; ++b)
                hl32[b * (HLS / 2) + tid] = (va[b] >> 16) | (vb[b] & 0xffff0000u);
        }
        __syncthreads();   // (B) hl[t] complete (h + x)

        // ---- MFMA: [h|x] (A, from LDS) x [W;W_in] (B, in regs), K=160 per wave ----
        f32x4 acc0 = {0.f, 0.f, 0.f, 0.f}, acc1 = {0.f, 0.f, 0.f, 0.f};
#pragma unroll
        for (int kt = 0; kt < 5; ++kt) {
            int k0 = (kt < 4) ? (wv * 128 + kt * 32) : (1024 + wv * 32);
            f16x8 av = *reinterpret_cast<const f16x8*>(&hl16[abase + k0]);
            acc0 = __builtin_amdgcn_mfma_f32_16x16x32_f16(av, bw[kt][0], acc0, 0, 0, 0);
            acc1 = __builtin_amdgcn_mfma_f32_16x16x32_f16(av, bw[kt][1], acc1, 0, 0, 0);
        }
        // C rows 0..3 = batches 0..3 live in lanes 0..15, regs 0..3
        if (lane < 16) {
            part4[wv * 32 + l15]      = acc0;   // cols c0 + 0..15
            part4[wv * 32 + 16 + l15] = acc1;   // cols c0 + 16..31
        }
        __syncthreads();   // (C) partials ready

        // ---- finalize + publish: lanes 0..31, one column x 4 batches ----
        if (tid < 32) {
            f32x4 s = part4[tid];
#pragma unroll
            for (int w2 = 1; w2 < 8; ++w2) s += part4[w2 * 32 + tid];
            float h0 = 0.8f * hs0 + 0.2f * tanh_fast(s[0]);
            float h1 = 0.8f * hs1 + 0.2f * tanh_fast(s[1]);
            float h2 = 0.8f * hs2 + 0.2f * tanh_fast(s[2]);
            float h3 = 0.8f * hs3 + 0.2f * tanh_fast(s[3]);
            hs0 = h0; hs1 = h1; hs2 = h2; hs3 = h3;
            size_t ob = ((size_t)b0 * T_ + t) * U_ + c0 + tid;
            out[ob]                       = h0;
            out[ob + (size_t)T_ * U_]     = h1;
            out[ob + (size_t)2 * T_ * U_] = h2;
            out[ob + (size_t)3 * T_ * U_] = h3;
            unsigned tg = (unsigned)(t + 1) & 0xffffu;
            u32x4 pk;
            pk[0] = ((unsigned)__builtin_bit_cast(unsigned short, (_Float16)h0) << 16) | tg;
            pk[1] = ((unsigned)__builtin_bit_cast(unsigned short, (_Float16)h1) << 16) | tg;
            pk[2] = ((unsigned)__builtin_bit_cast(unsigned short, (_Float16)h2) << 16) | tg;
            pk[3] = ((unsigned)__builtin_bit_cast(unsigned short, (_Float16)h3) << 16) | tg;
            u32x4* dst = hc + (size_t)((((t + 1) & 1) * 8192) + dom * 1024 + c0 + tid);
            asm volatile("global_store_dwordx4 %0, %1, off sc0 sc1"
                         :: "v"(dst), "v"(pk) : "memory");   // fire-and-forget
        }
    }
}

extern "C" void kernel_launch(void* const* d_in, const int* in_sizes, int n_in,
                              void* d_out, int out_size, void* d_ws, size_t ws_size,
                              hipStream_t stream) {
    const float* x   = (const float*)d_in[0];   // [32,1024,256]
    const float* W   = (const float*)d_in[1];   // [1024,1024]
    const float* win = (const float*)d_in[2];   // [256,1024]
    float* out = (float*)d_out;                 // [32,1024,1024]

    // ws: hcast ring = 2 slots x 8 dom x 1024 cols x 16 B = 256 KB (tag-checked, no init)
    u32x4* hc = (u32x4*)d_ws;
    if (ws_size < 2 * 8 * 1024 * 16) return;

    k_recur<<<dim3(256), dim3(NTHR), 0, stream>>>(x, W, win, out, hc);
}